// Round 2
// baseline (493.495 us; speedup 1.0000x reference)
//
#include <hip/hip_runtime.h>
#include <hip/hip_bf16.h>

#define B_DIM   16384
#define D_IN    1024
#define D_EXP   1024
#define D_TOW   512
#define N_EXPT  8
#define N_TASK  4

typedef _Float16 f16x8 __attribute__((ext_vector_type(8)));
typedef _Float16 f16x4 __attribute__((ext_vector_type(4)));
typedef float    f32x4 __attribute__((ext_vector_type(4)));

// ---------------- async global->LDS (16B per lane, wave-uniform LDS base) ---
__device__ __forceinline__ void gll16(const void* g, void* l) {
  __builtin_amdgcn_global_load_lds(
      (const __attribute__((address_space(1))) unsigned int*)g,
      (__attribute__((address_space(3))) unsigned int*)l,
      16, 0, 0);
}

// Fragment read from a swizzled [R][64] f16 LDS tile.
// Chunk swizzle: 16B chunk s within a 128B row holds global chunk s^(row&7).
__device__ __forceinline__ f16x8 ldfrag(const _Float16* sM, int rowbase, int ks, int lane) {
  int rl = rowbase + (lane & 15);
  int ch = ((ks << 2) + (lane >> 4)) ^ (rl & 7);
  return *(const f16x8*)&sM[rl * 64 + ch * 8];
}

// ---------------- prep: x -> f16, gates = x @ gate_w (fp32) ----------------
__global__ __launch_bounds__(256) void prep_x_kernel(
    const float* __restrict__ x, const float* __restrict__ gw,
    _Float16* __restrict__ xh, float* __restrict__ gates)
{
  __shared__ float sred[4][8];
  const int t = threadIdx.x;
  const long row = blockIdx.x;
  float4 v = ((const float4*)(x + row * D_IN))[t];
  f16x4 h;
  h[0] = (_Float16)v.x; h[1] = (_Float16)v.y; h[2] = (_Float16)v.z; h[3] = (_Float16)v.w;
  ((f16x4*)(xh + row * D_IN))[t] = h;

  float g[8];
#pragma unroll
  for (int e = 0; e < 8; ++e) g[e] = 0.f;
  const float* wp = gw + (size_t)t * 4 * 8;
  float xs[4] = {v.x, v.y, v.z, v.w};
#pragma unroll
  for (int j = 0; j < 4; ++j)
#pragma unroll
    for (int e = 0; e < 8; ++e) g[e] += xs[j] * wp[j * 8 + e];

#pragma unroll
  for (int e = 0; e < 8; ++e) {
    g[e] += __shfl_xor(g[e], 1);  g[e] += __shfl_xor(g[e], 2);
    g[e] += __shfl_xor(g[e], 4);  g[e] += __shfl_xor(g[e], 8);
    g[e] += __shfl_xor(g[e], 16); g[e] += __shfl_xor(g[e], 32);
  }
  if ((t & 63) == 0) {
#pragma unroll
    for (int e = 0; e < 8; ++e) sred[t >> 6][e] = g[e];
  }
  __syncthreads();
  if (t < 8) gates[row * 8 + t] = sred[0][t] + sred[1][t] + sred[2][t] + sred[3][t];
}

// ---------------- tiled transpose + fp32->f16: in[s][K][N] -> out[s][N][K] --
__global__ __launch_bounds__(256) void transpose_cvt_kernel(
    const float* __restrict__ in, _Float16* __restrict__ outp, int K, int N)
{
  __shared__ float tile[64][65];
  const int t = threadIdx.x;
  const int tx = t & 63, ty = t >> 6;
  const int n0 = blockIdx.x * 64;
  const int k0 = blockIdx.y * 64;
  const long s = blockIdx.z;
  const float* ip = in + s * (long)K * N;
  _Float16* op = outp + s * (long)K * N;
#pragma unroll
  for (int i = 0; i < 16; ++i) {
    int r = ty * 16 + i;
    tile[r][tx] = ip[(long)(k0 + r) * N + n0 + tx];
  }
  __syncthreads();
#pragma unroll
  for (int i = 0; i < 16; ++i) {
    int r = ty * 16 + i;
    op[(long)(n0 + r) * K + k0 + tx] = (_Float16)tile[tx][r];
  }
}

// ---------------- init d_out with tb2 --------------------------------------
__global__ void init_out_kernel(float* __restrict__ out, const float* __restrict__ tb2) {
  int i = blockIdx.x * 256 + threadIdx.x;
  if (i < N_TASK * B_DIM) out[i] = tb2[i >> 14];
}

// ---------------- fused experts + gate-weighted combine ---------------------
// shared[b,d] = sum_e gates[b,e] * relu(x[b,:] @ exp_w[e,:,d] + exp_b[e,d])
// BM=256, BN=128, BK=64; 8 waves (4M x 2N); 3-buffer depth-2 pipeline,
// counted vmcnt(6), one barrier per K-step, setprio around MFMA.
__global__ __launch_bounds__(512, 2) void moe_expert_kernel(
    const _Float16* __restrict__ xh,    // [B,1024]
    const _Float16* __restrict__ ewT,   // [8][n=1024][k=1024]
    const float* __restrict__ expb,     // [8][1024]
    const float* __restrict__ gates,    // [B][8]
    _Float16* __restrict__ shout)       // [B,1024] f16
{
  __shared__ alignas(16) _Float16 sAB[3][24576];   // per buf: A 256x64, B 128x64
  __shared__ float sG[256 * 8];
  __shared__ float sBias[8 * 128];
  const int t = threadIdx.x;
  const int lane = t & 63;
  const int wave = t >> 6;
  const int wm = wave >> 1, wn = wave & 1;
  const long row0 = (long)blockIdx.x * 256;
  const int col0 = blockIdx.y * 128;

  for (int i = t; i < 256 * 8; i += 512) sG[i] = gates[row0 * 8 + i];
  for (int i = t; i < 8 * 128; i += 512)
    sBias[i] = expb[(i >> 7) * D_EXP + col0 + (i & 127)];

  // per-thread constant source-swizzle offset
  const int so_t = (((t & 7) ^ ((t >> 3) & 7)) << 4);
  const char* aBase = (const char*)xh + row0 * 2048 + (size_t)(t >> 3) * 2048 + so_t;
  const char* bRoot = (const char*)ewT + (size_t)col0 * 2048 + (size_t)(t >> 3) * 2048 + so_t;

  char* p0 = (char*)&sAB[0][0];
  char* p1 = (char*)&sAB[1][0];
  char* p2 = (char*)&sAB[2][0];

  auto STAGE = [&](char* pS, int step) {
    int e = step >> 4, kk = step & 15;
    const char* ga = aBase + kk * 128;
    const char* gb = bRoot + (size_t)e * (D_IN * D_EXP * 2) + kk * 128;
#pragma unroll
    for (int r = 0; r < 4; ++r)
      gll16(ga + r * 131072, pS + r * 8192 + t * 16);
#pragma unroll
    for (int r = 0; r < 2; ++r)
      gll16(gb + r * 131072, pS + 32768 + r * 8192 + t * 16);
  };

  __syncthreads();   // sG/sBias visible; drains all init vmem (clean vmcnt)

  char *pRead = p0, *pNext = p1, *pStage = p2;
  STAGE(p0, 0);
  STAGE(p1, 1);

  f32x4 acc[4][4] = {};
  f32x4 shacc[4][4] = {};

  for (int i = 0; i < 128; ++i) {
    if (i < 127) { asm volatile("s_waitcnt vmcnt(6)" ::: "memory"); }
    else         { asm volatile("s_waitcnt vmcnt(0)" ::: "memory"); }
    __builtin_amdgcn_s_barrier();
    asm volatile("" ::: "memory");

    if (i < 126) STAGE(pStage, i + 2);

    const _Float16* bufA = (const _Float16*)pRead;
    const _Float16* bufB = bufA + 16384;

    __builtin_amdgcn_s_setprio(1);
#pragma unroll
    for (int ks = 0; ks < 2; ++ks) {
      f16x8 af[4], bf[4];
#pragma unroll
      for (int m = 0; m < 4; ++m) af[m] = ldfrag(bufA, wm * 64 + m * 16, ks, lane);
#pragma unroll
      for (int n = 0; n < 4; ++n) bf[n] = ldfrag(bufB, wn * 64 + n * 16, ks, lane);
#pragma unroll
      for (int m = 0; m < 4; ++m)
#pragma unroll
        for (int n = 0; n < 4; ++n)
          acc[m][n] = __builtin_amdgcn_mfma_f32_16x16x32_f16(af[m], bf[n], acc[m][n], 0, 0, 0);
    }
    __builtin_amdgcn_s_setprio(0);

    if ((i & 15) == 15) {
      const int e = i >> 4;
      float gv[4][4];
#pragma unroll
      for (int m = 0; m < 4; ++m) {
        int rbase = wm * 64 + m * 16 + ((lane >> 4) << 2);
#pragma unroll
        for (int r = 0; r < 4; ++r) gv[m][r] = sG[(rbase + r) * 8 + e];
      }
#pragma unroll
      for (int n = 0; n < 4; ++n) {
        float bias = sBias[e * 128 + wn * 64 + n * 16 + (lane & 15)];
#pragma unroll
        for (int m = 0; m < 4; ++m)
#pragma unroll
          for (int r = 0; r < 4; ++r) {
            float hv = acc[m][n][r] + bias;
            hv = hv > 0.f ? hv : 0.f;
            shacc[m][n][r] += gv[m][r] * hv;
            acc[m][n][r] = 0.f;
          }
      }
    }

    char* tmp = pRead; pRead = pNext; pNext = pStage; pStage = tmp;
  }

  // write shared tile as f16
#pragma unroll
  for (int m = 0; m < 4; ++m)
#pragma unroll
    for (int r = 0; r < 4; ++r) {
      long row = row0 + wm * 64 + m * 16 + ((lane >> 4) << 2) + r;
      _Float16* op = shout + row * D_EXP + col0 + wn * 64 + (lane & 15);
#pragma unroll
      for (int n = 0; n < 4; ++n) op[n * 16] = (_Float16)shacc[m][n][r];
    }
}

// ---------------- fused towers ----------------------------------------------
// out[task,b] += sum_h relu(shared[b,:] @ tw1[task,:,h] + tb1[task,h]) * tw2[task,h]
__global__ __launch_bounds__(512, 2) void moe_tower_kernel(
    const _Float16* __restrict__ sh,    // [B,1024] f16
    const _Float16* __restrict__ t1T,   // [4][h=512][d=1024] f16
    const float* __restrict__ tb1,      // [4][512]
    const float* __restrict__ tw2,      // [4][512]
    float* __restrict__ out)            // [4][B]
{
  __shared__ alignas(16) _Float16 sAB[3][24576];
  const int t = threadIdx.x;
  const int lane = t & 63;
  const int wave = t >> 6;
  const int wm = wave >> 1, wn = wave & 1;
  const long row0 = (long)blockIdx.x * 256;
  const int task = blockIdx.y >> 2;
  const int h0 = (blockIdx.y & 3) * 128;

  const int so_t = (((t & 7) ^ ((t >> 3) & 7)) << 4);
  const char* aBase = (const char*)sh + row0 * 2048 + (size_t)(t >> 3) * 2048 + so_t;
  const char* bBase = (const char*)t1T + (size_t)task * (D_TOW * D_EXP * 2)
                      + (size_t)h0 * 2048 + (size_t)(t >> 3) * 2048 + so_t;

  char* p0 = (char*)&sAB[0][0];
  char* p1 = (char*)&sAB[1][0];
  char* p2 = (char*)&sAB[2][0];

  auto STAGE = [&](char* pS, int kk) {
    const char* ga = aBase + kk * 128;
    const char* gb = bBase + kk * 128;
#pragma unroll
    for (int r = 0; r < 4; ++r)
      gll16(ga + r * 131072, pS + r * 8192 + t * 16);
#pragma unroll
    for (int r = 0; r < 2; ++r)
      gll16(gb + r * 131072, pS + 32768 + r * 8192 + t * 16);
  };

  __syncthreads();

  char *pRead = p0, *pNext = p1, *pStage = p2;
  STAGE(p0, 0);
  STAGE(p1, 1);

  f32x4 acc[4][4] = {};

  for (int i = 0; i < 16; ++i) {
    if (i < 15) { asm volatile("s_waitcnt vmcnt(6)" ::: "memory"); }
    else        { asm volatile("s_waitcnt vmcnt(0)" ::: "memory"); }
    __builtin_amdgcn_s_barrier();
    asm volatile("" ::: "memory");

    if (i < 14) STAGE(pStage, i + 2);

    const _Float16* bufA = (const _Float16*)pRead;
    const _Float16* bufB = bufA + 16384;

    __builtin_amdgcn_s_setprio(1);
#pragma unroll
    for (int ks = 0; ks < 2; ++ks) {
      f16x8 af[4], bf[4];
#pragma unroll
      for (int m = 0; m < 4; ++m) af[m] = ldfrag(bufA, wm * 64 + m * 16, ks, lane);
#pragma unroll
      for (int n = 0; n < 4; ++n) bf[n] = ldfrag(bufB, wn * 64 + n * 16, ks, lane);
#pragma unroll
      for (int m = 0; m < 4; ++m)
#pragma unroll
        for (int n = 0; n < 4; ++n)
          acc[m][n] = __builtin_amdgcn_mfma_f32_16x16x32_f16(af[m], bf[n], acc[m][n], 0, 0, 0);
    }
    __builtin_amdgcn_s_setprio(0);

    char* tmp = pRead; pRead = pNext; pNext = pStage; pStage = tmp;
  }

  float b1[4], w2[4];
#pragma unroll
  for (int n = 0; n < 4; ++n) {
    int col = h0 + wn * 64 + n * 16 + (lane & 15);
    b1[n] = tb1[task * D_TOW + col];
    w2[n] = tw2[task * D_TOW + col];
  }
#pragma unroll
  for (int m = 0; m < 4; ++m)
#pragma unroll
    for (int r = 0; r < 4; ++r) {
      float ssum = 0.f;
#pragma unroll
      for (int n = 0; n < 4; ++n) {
        float v = acc[m][n][r] + b1[n];
        v = v > 0.f ? v : 0.f;
        ssum += v * w2[n];
      }
      ssum += __shfl_xor(ssum, 1);
      ssum += __shfl_xor(ssum, 2);
      ssum += __shfl_xor(ssum, 4);
      ssum += __shfl_xor(ssum, 8);
      if ((lane & 15) == 0) {
        long row = row0 + wm * 64 + m * 16 + ((lane >> 4) << 2) + r;
        atomicAdd(&out[(size_t)task * B_DIM + row], ssum);
      }
    }
}

// ---------------- launch -----------------------------------------------------
extern "C" void kernel_launch(void* const* d_in, const int* in_sizes, int n_in,
                              void* d_out, int out_size, void* d_ws, size_t ws_size,
                              hipStream_t stream) {
  const float* x    = (const float*)d_in[0];
  const float* gw   = (const float*)d_in[1];
  const float* expw = (const float*)d_in[2];
  const float* expb = (const float*)d_in[3];
  const float* tw1  = (const float*)d_in[4];
  const float* tb1  = (const float*)d_in[5];
  const float* tw2  = (const float*)d_in[6];
  const float* tb2  = (const float*)d_in[7];
  float* out = (float*)d_out;

  char* ws = (char*)d_ws;
  _Float16* xh  = (_Float16*)ws;  ws += (size_t)B_DIM * D_IN * 2;          // 32 MB
  _Float16* ewT = (_Float16*)ws;  ws += (size_t)N_EXPT * D_IN * D_EXP * 2; // 16 MB
  _Float16* t1T = (_Float16*)ws;  ws += (size_t)N_TASK * D_TOW * D_EXP * 2; // 4 MB
  _Float16* shh = (_Float16*)ws;  ws += (size_t)B_DIM * D_EXP * 2;         // 32 MB
  float* gates  = (float*)ws;     ws += (size_t)B_DIM * N_EXPT * 4;        // 0.5 MB

  prep_x_kernel<<<B_DIM, 256, 0, stream>>>(x, gw, xh, gates);
  transpose_cvt_kernel<<<dim3(D_EXP / 64, D_IN / 64, N_EXPT), 256, 0, stream>>>(
      expw, ewT, D_IN, D_EXP);
  transpose_cvt_kernel<<<dim3(D_TOW / 64, D_EXP / 64, N_TASK), 256, 0, stream>>>(
      tw1, t1T, D_EXP, D_TOW);
  init_out_kernel<<<(N_TASK * B_DIM + 255) / 256, 256, 0, stream>>>(out, tb2);
  moe_expert_kernel<<<dim3(B_DIM / 256, D_EXP / 128), 512, 0, stream>>>(
      xh, ewT, expb, gates, shh);
  moe_tower_kernel<<<dim3(B_DIM / 256, (N_TASK * D_TOW) / 128), 512, 0, stream>>>(
      shh, t1T, tb1, tw2, out);
}

// Round 3
// 420.144 us; speedup vs baseline: 1.1746x; 1.1746x over previous
//
#include <hip/hip_runtime.h>
#include <hip/hip_bf16.h>

#define B_DIM   16384
#define D_IN    1024
#define D_EXP   1024
#define D_TOW   512
#define N_EXPT  8
#define N_TASK  4

typedef _Float16 f16x8 __attribute__((ext_vector_type(8)));
typedef _Float16 f16x4 __attribute__((ext_vector_type(4)));
typedef float    f32x4 __attribute__((ext_vector_type(4)));

// ---------------- async global->LDS (16B per lane, wave-uniform LDS base) ---
__device__ __forceinline__ void gll16(const void* g, void* l) {
  __builtin_amdgcn_global_load_lds(
      (const __attribute__((address_space(1))) unsigned int*)g,
      (__attribute__((address_space(3))) unsigned int*)l,
      16, 0, 0);
}

// Fragment read from a swizzled [rows][64] f16 LDS half-tile.
// 16B chunk s within a 128B row holds global chunk s^(row&7).
__device__ __forceinline__ f16x8 ldfrag(const _Float16* sM, int rowbase, int ks, int lane) {
  int rl = rowbase + (lane & 15);
  int ch = ((ks << 2) + (lane >> 4)) ^ (rl & 7);
  return *(const f16x8*)&sM[rl * 64 + ch * 8];
}

// ---------------- prep: x -> f16, gates = x @ gate_w (fp32) ----------------
__global__ __launch_bounds__(256) void prep_x_kernel(
    const float* __restrict__ x, const float* __restrict__ gw,
    _Float16* __restrict__ xh, float* __restrict__ gates)
{
  __shared__ float sred[4][8];
  const int t = threadIdx.x;
  const long row = blockIdx.x;
  float4 v = ((const float4*)(x + row * D_IN))[t];
  f16x4 h;
  h[0] = (_Float16)v.x; h[1] = (_Float16)v.y; h[2] = (_Float16)v.z; h[3] = (_Float16)v.w;
  ((f16x4*)(xh + row * D_IN))[t] = h;

  float g[8];
#pragma unroll
  for (int e = 0; e < 8; ++e) g[e] = 0.f;
  const float* wp = gw + (size_t)t * 4 * 8;
  float xs[4] = {v.x, v.y, v.z, v.w};
#pragma unroll
  for (int j = 0; j < 4; ++j)
#pragma unroll
    for (int e = 0; e < 8; ++e) g[e] += xs[j] * wp[j * 8 + e];

#pragma unroll
  for (int e = 0; e < 8; ++e) {
    g[e] += __shfl_xor(g[e], 1);  g[e] += __shfl_xor(g[e], 2);
    g[e] += __shfl_xor(g[e], 4);  g[e] += __shfl_xor(g[e], 8);
    g[e] += __shfl_xor(g[e], 16); g[e] += __shfl_xor(g[e], 32);
  }
  if ((t & 63) == 0) {
#pragma unroll
    for (int e = 0; e < 8; ++e) sred[t >> 6][e] = g[e];
  }
  __syncthreads();
  if (t < 8) gates[row * 8 + t] = sred[0][t] + sred[1][t] + sred[2][t] + sred[3][t];
}

// ---------------- tiled transpose + fp32->f16: in[s][K][N] -> out[s][N][K] --
__global__ __launch_bounds__(256) void transpose_cvt_kernel(
    const float* __restrict__ in, _Float16* __restrict__ outp, int K, int N)
{
  __shared__ float tile[64][65];
  const int t = threadIdx.x;
  const int tx = t & 63, ty = t >> 6;
  const int n0 = blockIdx.x * 64;
  const int k0 = blockIdx.y * 64;
  const long s = blockIdx.z;
  const float* ip = in + s * (long)K * N;
  _Float16* op = outp + s * (long)K * N;
#pragma unroll
  for (int i = 0; i < 16; ++i) {
    int r = ty * 16 + i;
    tile[r][tx] = ip[(long)(k0 + r) * N + n0 + tx];
  }
  __syncthreads();
#pragma unroll
  for (int i = 0; i < 16; ++i) {
    int r = ty * 16 + i;
    op[(long)(n0 + r) * K + k0 + tx] = (_Float16)tile[tx][r];
  }
}

// ---------------- init d_out with tb2 --------------------------------------
__global__ void init_out_kernel(float* __restrict__ out, const float* __restrict__ tb2) {
  int i = blockIdx.x * 256 + threadIdx.x;
  if (i < N_TASK * B_DIM) out[i] = tb2[i >> 14];
}

// ============ 8-phase-class pipelined GEMM phases (shared macro) ============
// Geometry: BM=256, BN=128, BK=64; 8 waves as 4M x 2N; per-wave C = 64x64.
// LDS slot (48KB): A0[128x64]@0, A1@8192, B0[64x64]@16384, B1@20480 (f16 idx).
// Iteration = 2 K-tiles x 2 half-phases; 16 MFMA per phase.
// Counted vmcnt(2) at P1/P3 end; stage schedule:
//   P0: s1.A0,A1 (this iter's kt1)   P1: s0.B0,B1 (kt0+2)
//   P2: s0.A0,A1 (kt0+2)             P3: s1.B0,B1 (kt1+2)
#define PHASE(SLOT, H, STAGES, WAITS)                                          \
  do {                                                                         \
    const _Float16* sAq = &sT[SLOT][(wm >> 1) * 8192];                         \
    const _Float16* sBq = &sT[SLOT][16384 + wn * 4096];                        \
    f16x8 af[2][2];                                                            \
    _Pragma("unroll") for (int m2 = 0; m2 < 2; ++m2)                           \
      _Pragma("unroll") for (int ks = 0; ks < 2; ++ks)                         \
        af[m2][ks] = ldfrag(sAq, (wm & 1) * 64 + ((H) * 2 + m2) * 16, ks, lane);\
    if ((H) == 0) {                                                            \
      _Pragma("unroll") for (int nf = 0; nf < 4; ++nf)                         \
        _Pragma("unroll") for (int ks = 0; ks < 2; ++ks)                       \
          bf[nf][ks] = ldfrag(sBq, nf * 16, ks, lane);                         \
    }                                                                          \
    STAGES;                                                                    \
    asm volatile("" ::: "memory");                                             \
    __builtin_amdgcn_s_barrier();                                              \
    asm volatile("s_waitcnt lgkmcnt(0)" ::: "memory");                         \
    __builtin_amdgcn_sched_barrier(0);                                         \
    __builtin_amdgcn_s_setprio(1);                                             \
    _Pragma("unroll") for (int m2 = 0; m2 < 2; ++m2)                           \
      _Pragma("unroll") for (int nf = 0; nf < 4; ++nf)                         \
        _Pragma("unroll") for (int ks = 0; ks < 2; ++ks)                       \
          acc[(H) * 2 + m2][nf] = __builtin_amdgcn_mfma_f32_16x16x32_f16(      \
              af[m2][ks], bf[nf][ks], acc[(H) * 2 + m2][nf], 0, 0, 0);         \
    __builtin_amdgcn_s_setprio(0);                                             \
    WAITS;                                                                     \
    asm volatile("" ::: "memory");                                             \
    __builtin_amdgcn_s_barrier();                                              \
  } while (0)

// ---------------- fused experts + gate-weighted combine ---------------------
__global__ __launch_bounds__(512, 2) void moe_expert_kernel(
    const _Float16* __restrict__ xh,    // [B,1024]
    const _Float16* __restrict__ ewT,   // [8][n=1024][k=1024]
    const float* __restrict__ expb,     // [8][1024]
    const float* __restrict__ gates,    // [B][8]
    _Float16* __restrict__ shout)       // [B,1024] f16
{
  __shared__ alignas(16) _Float16 sT[2][24576];   // 96KB: per slot A(32K)+B(16K)
  __shared__ float sG[256 * 8];
  __shared__ float sBias[8 * 128];
  const int t = threadIdx.x;
  const int lane = t & 63;
  const int wave = t >> 6;
  const int wm = wave >> 1, wn = wave & 1;
  const long row0 = (long)blockIdx.x * 256;
  const int col0 = blockIdx.y * 128;

  for (int i = t; i < 256 * 8; i += 512) sG[i] = gates[row0 * 8 + i];
  for (int i = t; i < 8 * 128; i += 512)
    sBias[i] = expb[(i >> 7) * D_EXP + col0 + (i & 127)];

  const int so_t = (((t & 7) ^ ((t >> 3) & 7)) << 4);
  const char* aBase = (const char*)xh + row0 * 2048 + (size_t)(t >> 3) * 2048 + so_t;
  const char* bRoot = (const char*)ewT + (size_t)col0 * 2048 + (size_t)(t >> 3) * 2048 + so_t;

  // A-half h = 128 rows (2 loads/thread); B-half h = 64 cols (1 load/thread)
  auto SA = [&](int s, int h, int step) {
    const char* g = aBase + (size_t)h * 262144 + (size_t)(step & 15) * 128;
    char* d = (char*)&sT[s][h * 8192] + t * 16;
    gll16(g, d);
    gll16(g + 131072, d + 8192);
    asm volatile("" ::: "memory");
  };
  auto SB = [&](int s, int h, int step) {
    const char* g = bRoot + (size_t)(step >> 4) * 2097152 + (size_t)h * 131072
                    + (size_t)(step & 15) * 128;
    char* d = (char*)&sT[s][16384 + h * 4096] + t * 16;
    gll16(g, d);
    asm volatile("" ::: "memory");
  };

  __syncthreads();   // sG/sBias visible; vmcnt drained -> clean FIFO

  // prologue: s0.B, s0.A (kt0=0), s1.B (kt1=1); s1.A staged at P0 of iter 0
  SB(0, 0, 0); SB(0, 1, 0);
  SA(0, 0, 0); SA(0, 1, 0);
  SB(1, 0, 1); SB(1, 1, 1);
  asm volatile("s_waitcnt vmcnt(2)" ::: "memory");
  __builtin_amdgcn_s_barrier();

  f32x4 acc[4][4] = {};
  f32x4 shacc[4][4] = {};
  f16x8 bf[4][2];

  for (int it = 0; it < 64; ++it) {
    const int kt1 = 2 * it + 1;
    const bool pf = (it < 63);

    PHASE(0, 0, { SA(1, 0, kt1); SA(1, 1, kt1); }, {});
    PHASE(0, 1, { if (pf) { SB(0, 0, 2 * it + 2); SB(0, 1, 2 * it + 2); } },
          { if (pf) { asm volatile("s_waitcnt vmcnt(2)" ::: "memory"); }
            else    { asm volatile("s_waitcnt vmcnt(0)" ::: "memory"); } });
    PHASE(1, 0, { if (pf) { SA(0, 0, 2 * it + 2); SA(0, 1, 2 * it + 2); } }, {});
    PHASE(1, 1, { if (pf) { SB(1, 0, 2 * it + 3); SB(1, 1, 2 * it + 3); } },
          { if (pf) { asm volatile("s_waitcnt vmcnt(2)" ::: "memory"); } });

    if ((it & 7) == 7) {
      const int e = it >> 3;
      float bias4[4];
#pragma unroll
      for (int nf = 0; nf < 4; ++nf)
        bias4[nf] = sBias[e * 128 + wn * 64 + nf * 16 + (lane & 15)];
#pragma unroll
      for (int mf = 0; mf < 4; ++mf) {
        int rbase = wm * 64 + mf * 16 + ((lane >> 4) << 2);
        float gv[4];
#pragma unroll
        for (int r = 0; r < 4; ++r) gv[r] = sG[(rbase + r) * 8 + e];
#pragma unroll
        for (int nf = 0; nf < 4; ++nf)
#pragma unroll
          for (int r = 0; r < 4; ++r) {
            float hv = acc[mf][nf][r] + bias4[nf];
            hv = hv > 0.f ? hv : 0.f;
            shacc[mf][nf][r] += gv[r] * hv;
            acc[mf][nf][r] = 0.f;
          }
      }
    }
  }

  // write shared tile as f16
#pragma unroll
  for (int mf = 0; mf < 4; ++mf)
#pragma unroll
    for (int r = 0; r < 4; ++r) {
      long row = row0 + wm * 64 + mf * 16 + ((lane >> 4) << 2) + r;
      _Float16* op = shout + row * D_EXP + col0 + wn * 64 + (lane & 15);
#pragma unroll
      for (int nf = 0; nf < 4; ++nf) op[nf * 16] = (_Float16)shacc[mf][nf][r];
    }
}

// ---------------- fused towers ----------------------------------------------
__global__ __launch_bounds__(512, 2) void moe_tower_kernel(
    const _Float16* __restrict__ sh,    // [B,1024] f16
    const _Float16* __restrict__ t1T,   // [4][h=512][d=1024] f16
    const float* __restrict__ tb1,      // [4][512]
    const float* __restrict__ tw2,      // [4][512]
    float* __restrict__ out)            // [4][B]
{
  __shared__ alignas(16) _Float16 sT[2][24576];
  const int t = threadIdx.x;
  const int lane = t & 63;
  const int wave = t >> 6;
  const int wm = wave >> 1, wn = wave & 1;
  const long row0 = (long)blockIdx.x * 256;
  const int task = blockIdx.y >> 2;
  const int col0 = (blockIdx.y & 3) * 128;

  float b1[4], w2[4];
#pragma unroll
  for (int nf = 0; nf < 4; ++nf) {
    int col = col0 + wn * 64 + nf * 16 + (lane & 15);
    b1[nf] = tb1[task * D_TOW + col];
    w2[nf] = tw2[task * D_TOW + col];
  }
  asm volatile("" ::: "memory");

  const int so_t = (((t & 7) ^ ((t >> 3) & 7)) << 4);
  const char* aBase = (const char*)sh + row0 * 2048 + (size_t)(t >> 3) * 2048 + so_t;
  const char* bRoot = (const char*)t1T + (size_t)task * (D_TOW * D_EXP * 2)
                      + (size_t)col0 * 2048 + (size_t)(t >> 3) * 2048 + so_t;

  auto SA = [&](int s, int h, int step) {
    const char* g = aBase + (size_t)h * 262144 + (size_t)step * 128;
    char* d = (char*)&sT[s][h * 8192] + t * 16;
    gll16(g, d);
    gll16(g + 131072, d + 8192);
    asm volatile("" ::: "memory");
  };
  auto SB = [&](int s, int h, int step) {
    const char* g = bRoot + (size_t)h * 131072 + (size_t)step * 128;
    char* d = (char*)&sT[s][16384 + h * 4096] + t * 16;
    gll16(g, d);
    asm volatile("" ::: "memory");
  };

  __syncthreads();

  SB(0, 0, 0); SB(0, 1, 0);
  SA(0, 0, 0); SA(0, 1, 0);
  SB(1, 0, 1); SB(1, 1, 1);
  asm volatile("s_waitcnt vmcnt(2)" ::: "memory");
  __builtin_amdgcn_s_barrier();

  f32x4 acc[4][4] = {};
  f16x8 bf[4][2];

  for (int it = 0; it < 8; ++it) {
    const int kt1 = 2 * it + 1;
    const bool pf = (it < 7);

    PHASE(0, 0, { SA(1, 0, kt1); SA(1, 1, kt1); }, {});
    PHASE(0, 1, { if (pf) { SB(0, 0, 2 * it + 2); SB(0, 1, 2 * it + 2); } },
          { if (pf) { asm volatile("s_waitcnt vmcnt(2)" ::: "memory"); }
            else    { asm volatile("s_waitcnt vmcnt(0)" ::: "memory"); } });
    PHASE(1, 0, { if (pf) { SA(0, 0, 2 * it + 2); SA(0, 1, 2 * it + 2); } }, {});
    PHASE(1, 1, { if (pf) { SB(1, 0, 2 * it + 3); SB(1, 1, 2 * it + 3); } },
          { if (pf) { asm volatile("s_waitcnt vmcnt(2)" ::: "memory"); } });
  }

#pragma unroll
  for (int mf = 0; mf < 4; ++mf)
#pragma unroll
    for (int r = 0; r < 4; ++r) {
      float ssum = 0.f;
#pragma unroll
      for (int nf = 0; nf < 4; ++nf) {
        float v = acc[mf][nf][r] + b1[nf];
        v = v > 0.f ? v : 0.f;
        ssum += v * w2[nf];
      }
      ssum += __shfl_xor(ssum, 1);
      ssum += __shfl_xor(ssum, 2);
      ssum += __shfl_xor(ssum, 4);
      ssum += __shfl_xor(ssum, 8);
      if ((lane & 15) == 0) {
        long row = row0 + wm * 64 + mf * 16 + ((lane >> 4) << 2) + r;
        atomicAdd(&out[(size_t)task * B_DIM + row], ssum);
      }
    }
}

// ---------------- launch -----------------------------------------------------
extern "C" void kernel_launch(void* const* d_in, const int* in_sizes, int n_in,
                              void* d_out, int out_size, void* d_ws, size_t ws_size,
                              hipStream_t stream) {
  const float* x    = (const float*)d_in[0];
  const float* gw   = (const float*)d_in[1];
  const float* expw = (const float*)d_in[2];
  const float* expb = (const float*)d_in[3];
  const float* tw1  = (const float*)d_in[4];
  const float* tb1  = (const float*)d_in[5];
  const float* tw2  = (const float*)d_in[6];
  const float* tb2  = (const float*)d_in[7];
  float* out = (float*)d_out;

  char* ws = (char*)d_ws;
  _Float16* xh  = (_Float16*)ws;  ws += (size_t)B_DIM * D_IN * 2;          // 32 MB
  _Float16* ewT = (_Float16*)ws;  ws += (size_t)N_EXPT * D_IN * D_EXP * 2; // 16 MB
  _Float16* t1T = (_Float16*)ws;  ws += (size_t)N_TASK * D_TOW * D_EXP * 2; // 4 MB
  _Float16* shh = (_Float16*)ws;  ws += (size_t)B_DIM * D_EXP * 2;         // 32 MB
  float* gates  = (float*)ws;     ws += (size_t)B_DIM * N_EXPT * 4;        // 0.5 MB

  prep_x_kernel<<<B_DIM, 256, 0, stream>>>(x, gw, xh, gates);
  transpose_cvt_kernel<<<dim3(D_EXP / 64, D_IN / 64, N_EXPT), 256, 0, stream>>>(
      expw, ewT, D_IN, D_EXP);
  transpose_cvt_kernel<<<dim3(D_TOW / 64, D_EXP / 64, N_TASK), 256, 0, stream>>>(
      tw1, t1T, D_EXP, D_TOW);
  init_out_kernel<<<(N_TASK * B_DIM + 255) / 256, 256, 0, stream>>>(out, tb2);
  moe_expert_kernel<<<dim3(B_DIM / 256, D_EXP / 128), 512, 0, stream>>>(
      xh, ewT, expb, gates, shh);
  moe_tower_kernel<<<dim3(B_DIM / 256, (N_TASK * D_TOW) / 128), 512, 0, stream>>>(
      shh, t1T, tb1, tw2, out);
}